// Round 10
// baseline (396.666 us; speedup 1.0000x reference)
//
#include <hip/hip_runtime.h>
#include <hip/hip_bf16.h>

// B=4, T=2048, SD=64, NE=4096, H=8, HS=8, FH=256. All reference reshapes are
// flat reinterpretations -> one flat buffer serves every "view".
// h/y/e/hf flat element (t,l): b*131072 + t*64 + l.
// x viewed (B,SD,SD,T): b*4194304 + i*131072 + j*2048 + t.
// out viewed (B,SD,SD,T): b*8388608 + i*131072 + j*2048 + t.
// Softmax: shift-invariant; fixed offset exp(qc-40) -> no global-max pass.
// part/esum are write-once partial buffers (no memset, no global atomics).

#define EPSF 1e-5f
#define OFFS 40.0f

// ------ K1: Feebler + LayerNorm1 + per-block column partial sums ------------
// 512 blocks, XCD-swizzled so the 4 b-blocks of one fw panel land on ONE XCD:
// bid = xcd + 8*slot; b = slot&3; panel = (slot>>2)*8 + xcd; i=panel&63.
__global__ void K1(const float* __restrict__ x, const float* __restrict__ fw,
                   const float* __restrict__ g, const float* __restrict__ bia,
                   float* __restrict__ h, float* __restrict__ y,
                   float* __restrict__ part) {
    int bid = blockIdx.x;
    int xcd = bid & 7, slot = bid >> 3;
    int b = slot & 3;
    int panel = (slot >> 2) * 8 + xcd;          // 0..127 = chunk*64 + i
    int i = panel & 63, chunk = panel >> 6;
    int t4 = chunk * 256 + threadIdx.x;         // float4 idx 0..511 in (b,i)
    const float4* x4 = (const float4*)x + (size_t)b * 2097152 + (size_t)i * 32768 + t4;
    const float4* f4 = (const float4*)fw + (size_t)i * 32768 + t4;
    float4 acc = make_float4(0.f, 0.f, 0.f, 0.f);
    #pragma unroll 8
    for (int j = 0; j < 64; ++j) {
        float4 xv = x4[(size_t)j * 512];
        float4 fv = f4[(size_t)j * 512];
        acc.x += xv.x * fv.x; acc.y += xv.y * fv.y;
        acc.z += xv.z * fv.z; acc.w += xv.w * fv.w;
    }
    float s1 = acc.x + acc.y + acc.z + acc.w;
    float s2 = acc.x * acc.x + acc.y * acc.y + acc.z * acc.z + acc.w * acc.w;
    for (int off = 8; off; off >>= 1) {
        s1 += __shfl_xor(s1, off);
        s2 += __shfl_xor(s2, off);
    }
    float m = s1 * (1.f / 64.f);
    float var = s2 * (1.f / 64.f) - m * m;
    float rs = rsqrtf(var + EPSF);
    float4 gv = ((const float4*)g)[t4 & 15];
    float4 bv = ((const float4*)bia)[t4 & 15];
    float4 yv;
    yv.x = (acc.x - m) * rs * gv.x + bv.x;
    yv.y = (acc.y - m) * rs * gv.y + bv.y;
    yv.z = (acc.z - m) * rs * gv.z + bv.z;
    yv.w = (acc.w - m) * rs * gv.w + bv.w;
    size_t oidx = (size_t)b * 32768 + (size_t)i * 512 + t4;
    ((float4*)h)[oidx] = acc;
    ((float4*)y)[oidx] = yv;
    __shared__ float ysL[64];
    if (threadIdx.x < 64) ysL[threadIdx.x] = 0.f;
    __syncthreads();
    int c0 = (t4 & 15) * 4;
    atomicAdd(&ysL[c0 + 0], yv.x);
    atomicAdd(&ysL[c0 + 1], yv.y);
    atomicAdd(&ysL[c0 + 2], yv.z);
    atomicAdd(&ysL[c0 + 3], yv.w);
    __syncthreads();
    if (threadIdx.x < 64)
        part[(panel * 4 + b) * 64 + threadIdx.x] = ysL[threadIdx.x];
}

// ------ K2: inline ck from part; e = exp((y@Wq)*ck - OFFS); esum partials ---
__global__ void K2(const float* __restrict__ y, const float* __restrict__ wq,
                   const float* __restrict__ wk, const float* __restrict__ part,
                   float* __restrict__ e, float* __restrict__ esum) {
    __shared__ float yT[64][20];
    __shared__ float wqL[64][64];
    __shared__ float psum[4][64];
    __shared__ float psA[4][64];
    __shared__ float ysL[64];
    int b = blockIdx.x, tile = blockIdx.y, t0 = tile * 16;
    int tid = threadIdx.x;
    int c = tid & 63, grp = tid >> 6;
    // reduce part -> ysum (this block's b)
    float sA = 0.f;
    for (int pp = 0; pp < 32; ++pp)
        sA += part[((grp * 32 + pp) * 4 + b) * 64 + c];
    psA[grp][c] = sA;
    for (int k = 0; k < 4; ++k) {
        int idx = k * 256 + tid;
        int r = idx >> 6, s = idx & 63;
        yT[s][r] = y[(size_t)b * 131072 + (size_t)(t0 + r) * 64 + s];
    }
    for (int k = 0; k < 16; ++k) {
        int idx = k * 256 + tid;
        int r = idx >> 6, cc = idx & 63;
        wqL[r][cc] = wq[(cc >> 3) * 512 + r * 8 + (cc & 7)];
    }
    __syncthreads();
    if (tid < 64)
        ysL[tid] = psA[0][tid] + psA[1][tid] + psA[2][tid] + psA[3][tid];
    __syncthreads();
    // ck for column c (4x redundant across grp, cheap)
    float ckc = 0.f;
    for (int s = 0; s < 64; ++s)
        ckc += ysL[s] * wk[(c >> 3) * 512 + s * 8 + (c & 7)];
    float acc[4] = {0.f, 0.f, 0.f, 0.f};
    for (int s = 0; s < 64; ++s) {
        float w = wqL[s][c];
        float4 a0 = *(const float4*)&yT[s][grp * 4];
        acc[0] += a0.x * w; acc[1] += a0.y * w;
        acc[2] += a0.z * w; acc[3] += a0.w * w;
    }
    float ls = 0.f;
    #pragma unroll
    for (int k = 0; k < 4; ++k) {
        float v = __expf(acc[k] * ckc - OFFS);
        e[(size_t)b * 131072 + (size_t)(t0 + grp * 4 + k) * 64 + c] = v;
        ls += v;
    }
    psum[grp][c] = ls;
    __syncthreads();
    if (tid < 64)
        esum[(b * 128 + tile) * 64 + tid] =
            psum[0][tid] + psum[1][tid] + psum[2][tid] + psum[3][tid];
}

// ------ K3: proj+LN2+FFN, 8 rows/thread (half the per-lane LDS reads) -------
// Grid (4,64): block = 32 rows, 4 waves x 8 rows, lane = column. ~60KB LDS ->
// 2 blocks/CU (8 waves/CU); kernel is LDS-throughput-bound so that suffices.
__global__ void __launch_bounds__(256, 2)
K3(const float* __restrict__ h, const float* __restrict__ e,
   const float* __restrict__ part, const float* __restrict__ esum,
   const float* __restrict__ wv, const float* __restrict__ projw,
   const float* __restrict__ projb, const float* __restrict__ g2,
   const float* __restrict__ b2l, const float* __restrict__ w1,
   const float* __restrict__ b1, const float* __restrict__ w2,
   const float* __restrict__ fb2, float* __restrict__ hf) {
    __shared__ float bufA[4096];       // projw, then w1 chunk [s][j]
    __shared__ float bufB[4096];       // w2 chunk [j][l]
    __shared__ float4 pT[4][64][2];    // 8 p-rows per (w,col)
    __shared__ float4 y2T[4][64][2];
    __shared__ float4 hidT[4][64][2];
    __shared__ float psA[4][64], psE[4][64];
    __shared__ float ysL[64], denL[64];
    int b = blockIdx.x, chunk = blockIdx.y;
    int tid = threadIdx.x, l = tid & 63, w = tid >> 6;

    // stage projw (16KB)
    float4* bufA4 = (float4*)bufA;
    const float4* pw4 = (const float4*)projw;
    #pragma unroll
    for (int k = 0; k < 4; ++k) bufA4[k * 256 + tid] = pw4[k * 256 + tid];
    // partial reduces for ysum (->cv) and den
    float sA = 0.f, sE = 0.f;
    for (int pp = 0; pp < 32; ++pp) {
        sA += part[((w * 32 + pp) * 4 + b) * 64 + l];
        sE += esum[(b * 128 + w * 32 + pp) * 64 + l];
    }
    psA[w][l] = sA;
    psE[w][l] = sE;
    __syncthreads();
    if (tid < 64) {
        ysL[tid] = psA[0][tid] + psA[1][tid] + psA[2][tid] + psA[3][tid];
        denL[tid] = psE[0][tid] + psE[1][tid] + psE[2][tid] + psE[3][tid];
    }
    __syncthreads();
    float cvv = 0.f;
    for (int s = 0; s < 64; ++s)
        cvv += ysL[s] * wv[(l >> 3) * 512 + s * 8 + (l & 7)];
    float sc = cvv / denL[l];

    size_t base = (size_t)b * 131072 + (size_t)(chunk * 32 + w * 8) * 64 + l;
    float hr[8], pr[8];
    #pragma unroll
    for (int rr = 0; rr < 8; ++rr) {
        pr[rr] = e[base + rr * 64] * sc;
        hr[rr] = h[base + rr * 64];
    }
    pT[w][l][0] = make_float4(pr[0], pr[1], pr[2], pr[3]);
    pT[w][l][1] = make_float4(pr[4], pr[5], pr[6], pr[7]);
    __syncthreads();

    // proj from LDS: 64 iters x (1 per-lane b32 + 2 broadcast b128 + 8 FMA)
    float a[8] = {0.f, 0.f, 0.f, 0.f, 0.f, 0.f, 0.f, 0.f};
    for (int c = 0; c < 64; ++c) {
        float4 p0 = pT[w][c][0];
        float4 p1 = pT[w][c][1];
        float pw = bufA[c * 64 + l];
        a[0] += p0.x * pw; a[1] += p0.y * pw; a[2] += p0.z * pw; a[3] += p0.w * pw;
        a[4] += p1.x * pw; a[5] += p1.y * pw; a[6] += p1.z * pw; a[7] += p1.w * pw;
    }
    float pb = projb[l], g2v = g2[l], b2v = b2l[l];
    float hmid[8], y2[8];
    #pragma unroll
    for (int rr = 0; rr < 8; ++rr) {
        hmid[rr] = hr[rr] + a[rr] + pb;
        float v = hmid[rr];
        float s1 = v, s2 = v * v;
        for (int off = 32; off; off >>= 1) {
            s1 += __shfl_xor(s1, off);
            s2 += __shfl_xor(s2, off);
        }
        float mm = s1 * (1.f / 64.f);
        float var = s2 * (1.f / 64.f) - mm * mm;
        float rs = rsqrtf(var + EPSF);
        y2[rr] = (v - mm) * rs * g2v + b2v;
    }
    y2T[w][l][0] = make_float4(y2[0], y2[1], y2[2], y2[3]);
    y2T[w][l][1] = make_float4(y2[4], y2[5], y2[6], y2[7]);
    __syncthreads();   // proj done with bufA; y2T visible

    // FFN in 4 chunks of 64 hidden units, weights staged in LDS
    float4* bufB4 = (float4*)bufB;
    const float4* w14 = (const float4*)w1;
    const float4* w24 = (const float4*)w2;
    float a2[8] = {0.f, 0.f, 0.f, 0.f, 0.f, 0.f, 0.f, 0.f};
    for (int c4 = 0; c4 < 4; ++c4) {
        #pragma unroll
        for (int k = 0; k < 4; ++k) {
            int f = k * 256 + tid;
            int r = f >> 4, q = f & 15;
            bufA4[r * 16 + q] = w14[r * 64 + c4 * 16 + q];           // w1c[s][j]
            bufB4[r * 16 + q] = w24[(size_t)(c4 * 64 + r) * 16 + q]; // w2c[j][l]
        }
        __syncthreads();
        float bb = b1[c4 * 64 + l];
        float hc[8] = {bb, bb, bb, bb, bb, bb, bb, bb};
        for (int s = 0; s < 64; ++s) {
            float4 y0 = y2T[w][s][0];
            float4 y1 = y2T[w][s][1];
            float w1v = bufA[s * 64 + l];
            hc[0] += y0.x * w1v; hc[1] += y0.y * w1v;
            hc[2] += y0.z * w1v; hc[3] += y0.w * w1v;
            hc[4] += y1.x * w1v; hc[5] += y1.y * w1v;
            hc[6] += y1.z * w1v; hc[7] += y1.w * w1v;
        }
        hidT[w][l][0] = make_float4(fmaxf(hc[0], 0.f), fmaxf(hc[1], 0.f),
                                    fmaxf(hc[2], 0.f), fmaxf(hc[3], 0.f));
        hidT[w][l][1] = make_float4(fmaxf(hc[4], 0.f), fmaxf(hc[5], 0.f),
                                    fmaxf(hc[6], 0.f), fmaxf(hc[7], 0.f));
        for (int j = 0; j < 64; ++j) {          // same-wave LDS, no barrier
            float4 h0 = hidT[w][j][0];
            float4 h1 = hidT[w][j][1];
            float w2v = bufB[j * 64 + l];
            a2[0] += h0.x * w2v; a2[1] += h0.y * w2v;
            a2[2] += h0.z * w2v; a2[3] += h0.w * w2v;
            a2[4] += h1.x * w2v; a2[5] += h1.y * w2v;
            a2[6] += h1.z * w2v; a2[7] += h1.w * w2v;
        }
        __syncthreads();   // protect bufA/bufB for next chunk
    }
    float fb = fb2[l];
    #pragma unroll
    for (int rr = 0; rr < 8; ++rr)
        hf[base + rr * 64] = hmid[rr] + a2[rr] + fb;
}

// ------ K5: Booster. out[b,i,j,t'] = bw[i,j,t'] * hf[b, j*2048+t'] ----------
// Each bw float4 read by exactly one thread; loop b inside (hf L2/L3-resident).
__global__ void K5(const float* __restrict__ hf, const float* __restrict__ bw,
                   float* __restrict__ out) {
    int wi = blockIdx.x * 256 + threadIdx.x;    // float4 index into bw
    int i = wi >> 15;
    int jt = wi & 32767;                        // j*512 + t4
    const float4* bw4 = (const float4*)bw;
    const float4* hf4 = (const float4*)hf;
    float4* o4 = (float4*)out;
    float4 wv = bw4[wi];
    size_t obase = (size_t)i * 32768 + jt;
    #pragma unroll
    for (int b = 0; b < 4; ++b) {
        float4 hv = hf4[b * 32768 + jt];
        float4 ov;
        ov.x = wv.x * hv.x; ov.y = wv.y * hv.y;
        ov.z = wv.z * hv.z; ov.w = wv.w * hv.w;
        o4[(size_t)b * 2097152 + obase] = ov;
    }
}

extern "C" void kernel_launch(void* const* d_in, const int* in_sizes, int n_in,
                              void* d_out, int out_size, void* d_ws, size_t ws_size,
                              hipStream_t stream) {
    const float* x     = (const float*)d_in[0];
    const float* fw    = (const float*)d_in[1];
    const float* bw    = (const float*)d_in[2];
    const float* wq    = (const float*)d_in[3];
    const float* wk    = (const float*)d_in[4];
    const float* wv    = (const float*)d_in[5];
    const float* projw = (const float*)d_in[6];
    const float* projb = (const float*)d_in[7];
    const float* g1    = (const float*)d_in[8];
    const float* b1l   = (const float*)d_in[9];
    const float* g2    = (const float*)d_in[10];
    const float* b2l   = (const float*)d_in[11];
    const float* w1    = (const float*)d_in[12];
    const float* b1    = (const float*)d_in[13];
    const float* w2    = (const float*)d_in[14];
    const float* b2    = (const float*)d_in[15];
    float* out = (float*)d_out;

    float* wsf = (float*)d_ws;
    float* h    = wsf;                 // 524288
    float* y    = wsf + 524288;        // 524288 (reused as hf after K2)
    float* hf   = wsf + 524288;        //   - y dead after K2; hf live K3->K5
    float* e    = wsf + 1048576;       // 524288
    float* part = wsf + 1572864;       // 32768 (128 panels x 4 b x 64)
    float* esum = wsf + 1605632;       // 32768

    K1<<<512, 256, 0, stream>>>(x, fw, g1, b1l, h, y, part);
    K2<<<dim3(4, 128), 256, 0, stream>>>(y, wq, wk, part, e, esum);
    K3<<<dim3(4, 64), 256, 0, stream>>>(h, e, part, esum, wv, projw, projb,
                                        g2, b2l, w1, b1, w2, b2, hf);
    K5<<<8192, 256, 0, stream>>>(hf, bw, out);
}

// Round 11
// 143.083 us; speedup vs baseline: 2.7723x; 2.7723x over previous
//
#include <hip/hip_runtime.h>
#include <hip/hip_bf16.h>

// B=4, T=2048, SD=64, NE=4096, H=8, HS=8, FH=256. All reference reshapes are
// flat reinterpretations -> one flat buffer serves every "view".
// h/y/e/hf flat element (t,l): b*131072 + t*64 + l.
// x viewed (B,SD,SD,T): b*4194304 + i*131072 + j*2048 + t.
// out viewed (B,SD,SD,T): b*8388608 + i*131072 + j*2048 + t.
// Softmax: shift-invariant; fixed offset exp(qc-40) -> no global-max pass.
// This is the best-measured configuration (R6, 137 µs): R10's 8-row K3
// register blocking spilled to scratch (VGPR cap 128, 388 MB scratch writes).

#define EPSF 1e-5f
#define OFFS 40.0f

// ------ K1: Feebler + LayerNorm1 + per-block column partial sums ------------
// 512 blocks, XCD-swizzled so the 4 b-blocks of one fw panel land on ONE XCD:
// bid = xcd + 8*slot; b = slot&3; panel = (slot>>2)*8 + xcd; i=panel&63.
__global__ void K1(const float* __restrict__ x, const float* __restrict__ fw,
                   const float* __restrict__ g, const float* __restrict__ bia,
                   float* __restrict__ h, float* __restrict__ y,
                   float* __restrict__ part) {
    int bid = blockIdx.x;
    int xcd = bid & 7, slot = bid >> 3;
    int b = slot & 3;
    int panel = (slot >> 2) * 8 + xcd;          // 0..127 = chunk*64 + i
    int i = panel & 63, chunk = panel >> 6;
    int t4 = chunk * 256 + threadIdx.x;         // float4 idx 0..511 in (b,i)
    const float4* x4 = (const float4*)x + (size_t)b * 2097152 + (size_t)i * 32768 + t4;
    const float4* f4 = (const float4*)fw + (size_t)i * 32768 + t4;
    float4 acc = make_float4(0.f, 0.f, 0.f, 0.f);
    #pragma unroll 8
    for (int j = 0; j < 64; ++j) {
        float4 xv = x4[(size_t)j * 512];
        float4 fv = f4[(size_t)j * 512];
        acc.x += xv.x * fv.x; acc.y += xv.y * fv.y;
        acc.z += xv.z * fv.z; acc.w += xv.w * fv.w;
    }
    float s1 = acc.x + acc.y + acc.z + acc.w;
    float s2 = acc.x * acc.x + acc.y * acc.y + acc.z * acc.z + acc.w * acc.w;
    for (int off = 8; off; off >>= 1) {
        s1 += __shfl_xor(s1, off);
        s2 += __shfl_xor(s2, off);
    }
    float m = s1 * (1.f / 64.f);
    float var = s2 * (1.f / 64.f) - m * m;
    float rs = rsqrtf(var + EPSF);
    float4 gv = ((const float4*)g)[t4 & 15];
    float4 bv = ((const float4*)bia)[t4 & 15];
    float4 yv;
    yv.x = (acc.x - m) * rs * gv.x + bv.x;
    yv.y = (acc.y - m) * rs * gv.y + bv.y;
    yv.z = (acc.z - m) * rs * gv.z + bv.z;
    yv.w = (acc.w - m) * rs * gv.w + bv.w;
    size_t oidx = (size_t)b * 32768 + (size_t)i * 512 + t4;
    ((float4*)h)[oidx] = acc;
    ((float4*)y)[oidx] = yv;
    __shared__ float ysL[64];
    if (threadIdx.x < 64) ysL[threadIdx.x] = 0.f;
    __syncthreads();
    int c0 = (t4 & 15) * 4;
    atomicAdd(&ysL[c0 + 0], yv.x);
    atomicAdd(&ysL[c0 + 1], yv.y);
    atomicAdd(&ysL[c0 + 2], yv.z);
    atomicAdd(&ysL[c0 + 3], yv.w);
    __syncthreads();
    if (threadIdx.x < 64)
        part[(panel * 4 + b) * 64 + threadIdx.x] = ysL[threadIdx.x];
}

// ------ K2: inline ck from part; e = exp((y@Wq)*ck - OFFS); esum partials ---
__global__ void K2(const float* __restrict__ y, const float* __restrict__ wq,
                   const float* __restrict__ wk, const float* __restrict__ part,
                   float* __restrict__ e, float* __restrict__ esum) {
    __shared__ float yT[64][20];
    __shared__ float wqL[64][64];
    __shared__ float psum[4][64];
    __shared__ float psA[4][64];
    __shared__ float ysL[64];
    int b = blockIdx.x, tile = blockIdx.y, t0 = tile * 16;
    int tid = threadIdx.x;
    int c = tid & 63, grp = tid >> 6;
    // reduce part -> ysum (this block's b)
    float sA = 0.f;
    for (int pp = 0; pp < 32; ++pp)
        sA += part[((grp * 32 + pp) * 4 + b) * 64 + c];
    psA[grp][c] = sA;
    for (int k = 0; k < 4; ++k) {
        int idx = k * 256 + tid;
        int r = idx >> 6, s = idx & 63;
        yT[s][r] = y[(size_t)b * 131072 + (size_t)(t0 + r) * 64 + s];
    }
    for (int k = 0; k < 16; ++k) {
        int idx = k * 256 + tid;
        int r = idx >> 6, cc = idx & 63;
        wqL[r][cc] = wq[(cc >> 3) * 512 + r * 8 + (cc & 7)];
    }
    __syncthreads();
    if (tid < 64)
        ysL[tid] = psA[0][tid] + psA[1][tid] + psA[2][tid] + psA[3][tid];
    __syncthreads();
    // ck for column c (4x redundant across grp, cheap)
    float ckc = 0.f;
    for (int s = 0; s < 64; ++s)
        ckc += ysL[s] * wk[(c >> 3) * 512 + s * 8 + (c & 7)];
    float acc[4] = {0.f, 0.f, 0.f, 0.f};
    for (int s = 0; s < 64; ++s) {
        float w = wqL[s][c];
        float4 a0 = *(const float4*)&yT[s][grp * 4];
        acc[0] += a0.x * w; acc[1] += a0.y * w;
        acc[2] += a0.z * w; acc[3] += a0.w * w;
    }
    float ls = 0.f;
    #pragma unroll
    for (int k = 0; k < 4; ++k) {
        float v = __expf(acc[k] * ckc - OFFS);
        e[(size_t)b * 131072 + (size_t)(t0 + grp * 4 + k) * 64 + c] = v;
        ls += v;
    }
    psum[grp][c] = ls;
    __syncthreads();
    if (tid < 64)
        esum[(b * 128 + tile) * 64 + tid] =
            psum[0][tid] + psum[1][tid] + psum[2][tid] + psum[3][tid];
}

// ------ K3m: inline cv/scl; proj+LN2+FFN (LDS weights) -> hf ----------------
// Block (b, chunk of 16 rows): 4 waves x 4 rows. ~46KB LDS -> 3 blocks/CU.
__global__ void __launch_bounds__(256, 3)
K3m(const float* __restrict__ h, const float* __restrict__ e,
    const float* __restrict__ part, const float* __restrict__ esum,
    const float* __restrict__ wv, const float* __restrict__ projw,
    const float* __restrict__ projb, const float* __restrict__ g2,
    const float* __restrict__ b2l, const float* __restrict__ w1,
    const float* __restrict__ b1, const float* __restrict__ w2,
    const float* __restrict__ fb2, float* __restrict__ hf) {
    __shared__ float bufA[4096];      // projw, then w1 chunk [s][j]
    __shared__ float bufB[4096];      // w2 chunk [j][l]
    __shared__ float4 pT[4][64];
    __shared__ float4 y2T[4][64];
    __shared__ float4 hidT[4][64];
    __shared__ float psA[4][64], psE[4][64];
    __shared__ float ysL[64], denL[64];
    int b = blockIdx.x, chunk = blockIdx.y;
    int tid = threadIdx.x, l = tid & 63, w = tid >> 6;

    // stage projw
    float4* bufA4 = (float4*)bufA;
    const float4* pw4 = (const float4*)projw;
    #pragma unroll
    for (int k = 0; k < 4; ++k) bufA4[k * 256 + tid] = pw4[k * 256 + tid];
    // partial reduces for ysum (->cv) and den
    float sA = 0.f, sE = 0.f;
    for (int pp = 0; pp < 32; ++pp) {
        sA += part[((w * 32 + pp) * 4 + b) * 64 + l];
        sE += esum[(b * 128 + w * 32 + pp) * 64 + l];
    }
    psA[w][l] = sA;
    psE[w][l] = sE;
    __syncthreads();
    if (tid < 64) {
        ysL[tid] = psA[0][tid] + psA[1][tid] + psA[2][tid] + psA[3][tid];
        denL[tid] = psE[0][tid] + psE[1][tid] + psE[2][tid] + psE[3][tid];
    }
    __syncthreads();
    float cvv = 0.f;
    for (int s = 0; s < 64; ++s)
        cvv += ysL[s] * wv[(l >> 3) * 512 + s * 8 + (l & 7)];
    float sc = cvv / denL[l];

    size_t base = (size_t)b * 131072 + (size_t)(chunk * 16 + w * 4) * 64 + l;
    float4 p;
    p.x = e[base] * sc;
    p.y = e[base + 64] * sc;
    p.z = e[base + 128] * sc;
    p.w = e[base + 192] * sc;
    pT[w][l] = p;
    float h0 = h[base], h1r = h[base + 64], h2r = h[base + 128], h3r = h[base + 192];
    __syncthreads();

    // proj from LDS
    float a[4] = {0.f, 0.f, 0.f, 0.f};
    for (int c = 0; c < 64; ++c) {
        float4 pv = pT[w][c];
        float pw = bufA[c * 64 + l];
        a[0] += pv.x * pw; a[1] += pv.y * pw;
        a[2] += pv.z * pw; a[3] += pv.w * pw;
    }
    float pb = projb[l], g2v = g2[l], b2v = b2l[l];
    float hmid[4] = {h0 + a[0] + pb, h1r + a[1] + pb, h2r + a[2] + pb, h3r + a[3] + pb};
    float y2[4];
    #pragma unroll
    for (int rr = 0; rr < 4; ++rr) {
        float v = hmid[rr];
        float s1 = v, s2 = v * v;
        for (int off = 32; off; off >>= 1) {
            s1 += __shfl_xor(s1, off);
            s2 += __shfl_xor(s2, off);
        }
        float mm = s1 * (1.f / 64.f);
        float var = s2 * (1.f / 64.f) - mm * mm;
        float rs = rsqrtf(var + EPSF);
        y2[rr] = (v - mm) * rs * g2v + b2v;
    }
    y2T[w][l] = make_float4(y2[0], y2[1], y2[2], y2[3]);
    __syncthreads();   // proj done with bufA; y2T visible

    // FFN in 4 chunks of 64 hidden units
    float4* bufB4 = (float4*)bufB;
    const float4* w14 = (const float4*)w1;
    const float4* w24 = (const float4*)w2;
    float a2[4] = {0.f, 0.f, 0.f, 0.f};
    for (int c4 = 0; c4 < 4; ++c4) {
        #pragma unroll
        for (int k = 0; k < 4; ++k) {
            int f = k * 256 + tid;
            int r = f >> 4, q = f & 15;
            bufA4[r * 16 + q] = w14[r * 64 + c4 * 16 + q];           // w1c[s][j]
            bufB4[r * 16 + q] = w24[(size_t)(c4 * 64 + r) * 16 + q]; // w2c[j][l]
        }
        __syncthreads();
        float bb = b1[c4 * 64 + l];
        float hc[4] = {bb, bb, bb, bb};
        for (int s = 0; s < 64; ++s) {
            float4 yv = y2T[w][s];
            float w1v = bufA[s * 64 + l];
            hc[0] += yv.x * w1v; hc[1] += yv.y * w1v;
            hc[2] += yv.z * w1v; hc[3] += yv.w * w1v;
        }
        hidT[w][l] = make_float4(fmaxf(hc[0], 0.f), fmaxf(hc[1], 0.f),
                                 fmaxf(hc[2], 0.f), fmaxf(hc[3], 0.f));
        for (int j = 0; j < 64; ++j) {          // same-wave LDS, no barrier
            float4 hv = hidT[w][j];
            float w2v = bufB[j * 64 + l];
            a2[0] += hv.x * w2v; a2[1] += hv.y * w2v;
            a2[2] += hv.z * w2v; a2[3] += hv.w * w2v;
        }
        __syncthreads();   // protect bufA/bufB for next chunk
    }
    float fb = fb2[l];
    hf[base]       = hmid[0] + a2[0] + fb;
    hf[base + 64]  = hmid[1] + a2[1] + fb;
    hf[base + 128] = hmid[2] + a2[2] + fb;
    hf[base + 192] = hmid[3] + a2[3] + fb;
}

// ------ K5: Booster. out[b,i,j,t'] = bw[i,j,t'] * hf[b, j*2048+t'] ----------
// Each bw float4 read by exactly one thread; loop b inside (hf L2/L3-resident).
__global__ void K5(const float* __restrict__ hf, const float* __restrict__ bw,
                   float* __restrict__ out) {
    int wi = blockIdx.x * 256 + threadIdx.x;    // 0 .. 2M-1 float4 index into bw
    int i = wi >> 15;
    int jt = wi & 32767;                        // j*512 + t4
    const float4* bw4 = (const float4*)bw;
    const float4* hf4 = (const float4*)hf;
    float4* o4 = (float4*)out;
    float4 wv = bw4[wi];
    size_t obase = (size_t)i * 32768 + jt;
    #pragma unroll
    for (int b = 0; b < 4; ++b) {
        float4 hv = hf4[b * 32768 + jt];
        float4 ov;
        ov.x = wv.x * hv.x; ov.y = wv.y * hv.y;
        ov.z = wv.z * hv.z; ov.w = wv.w * hv.w;
        o4[(size_t)b * 2097152 + obase] = ov;
    }
}

extern "C" void kernel_launch(void* const* d_in, const int* in_sizes, int n_in,
                              void* d_out, int out_size, void* d_ws, size_t ws_size,
                              hipStream_t stream) {
    const float* x     = (const float*)d_in[0];
    const float* fw    = (const float*)d_in[1];
    const float* bw    = (const float*)d_in[2];
    const float* wq    = (const float*)d_in[3];
    const float* wk    = (const float*)d_in[4];
    const float* wv    = (const float*)d_in[5];
    const float* projw = (const float*)d_in[6];
    const float* projb = (const float*)d_in[7];
    const float* g1    = (const float*)d_in[8];
    const float* b1l   = (const float*)d_in[9];
    const float* g2    = (const float*)d_in[10];
    const float* b2l   = (const float*)d_in[11];
    const float* w1    = (const float*)d_in[12];
    const float* b1    = (const float*)d_in[13];
    const float* w2    = (const float*)d_in[14];
    const float* b2    = (const float*)d_in[15];
    float* out = (float*)d_out;

    float* wsf = (float*)d_ws;
    float* h    = wsf;                 // 524288
    float* y    = wsf + 524288;        // 524288 (reused as hf after K2)
    float* hf   = wsf + 524288;        //   - y dead after K2; hf live K3m->K5
    float* e    = wsf + 1048576;       // 524288
    float* part = wsf + 1572864;       // 32768
    float* esum = wsf + 1605632;       // 32768

    K1 <<<512, 256, 0, stream>>>(x, fw, g1, b1l, h, y, part);
    K2 <<<dim3(4, 128), 256, 0, stream>>>(y, wq, wk, part, e, esum);
    K3m<<<dim3(4, 128), 256, 0, stream>>>(h, e, part, esum, wv, projw, projb,
                                          g2, b2l, w1, b1, w2, b2, hf);
    K5 <<<8192, 256, 0, stream>>>(hf, bw, out);
}

// Round 13
// 121.504 us; speedup vs baseline: 3.2646x; 1.1776x over previous
//
#include <hip/hip_runtime.h>
#include <hip/hip_bf16.h>

// B=4, T=2048, SD=64, NE=4096, H=8, HS=8, FH=256. All reference reshapes are
// flat reinterpretations -> one flat buffer serves every "view".
// h/y/e/hf flat element (t,l): b*131072 + t*64 + l.
// x viewed (B,SD,SD,T): b*4194304 + i*131072 + j*2048 + t.
// out viewed (B,SD,SD,T): b*8388608 + i*131072 + j*2048 + t.
// Softmax: shift-invariant; fixed offset exp(qc-40) -> no global-max pass.
// R6 structure (best measured 137us) + nontemporal hints on stream-once
// traffic (x reads, bw reads, out writes); nontemporal builtins need a
// native ext_vector_type, not HIP_vector_type (R12 compile fix).

#define EPSF 1e-5f
#define OFFS 40.0f

typedef float vfloat4 __attribute__((ext_vector_type(4)));

__device__ __forceinline__ float4 ntload4(const float4* p) {
    vfloat4 v = __builtin_nontemporal_load((const vfloat4*)p);
    return make_float4(v.x, v.y, v.z, v.w);
}
__device__ __forceinline__ void ntstore4(float4* p, float4 v) {
    vfloat4 t = {v.x, v.y, v.z, v.w};
    __builtin_nontemporal_store(t, (vfloat4*)p);
}

// ------ K1: Feebler + LayerNorm1 + per-block column partial sums ------------
// 512 blocks, XCD-swizzled so the 4 b-blocks of one fw panel land on ONE XCD:
// bid = xcd + 8*slot; b = slot&3; panel = (slot>>2)*8 + xcd; i=panel&63.
__global__ void K1(const float* __restrict__ x, const float* __restrict__ fw,
                   const float* __restrict__ g, const float* __restrict__ bia,
                   float* __restrict__ h, float* __restrict__ y,
                   float* __restrict__ part) {
    int bid = blockIdx.x;
    int xcd = bid & 7, slot = bid >> 3;
    int b = slot & 3;
    int panel = (slot >> 2) * 8 + xcd;          // 0..127 = chunk*64 + i
    int i = panel & 63, chunk = panel >> 6;
    int t4 = chunk * 256 + threadIdx.x;         // float4 idx 0..511 in (b,i)
    const float4* x4 = (const float4*)x + (size_t)b * 2097152 + (size_t)i * 32768 + t4;
    const float4* f4 = (const float4*)fw + (size_t)i * 32768 + t4;
    float4 acc = make_float4(0.f, 0.f, 0.f, 0.f);
    #pragma unroll 8
    for (int j = 0; j < 64; ++j) {
        float4 xv = ntload4(&x4[(size_t)j * 512]);   // read-once stream
        float4 fv = f4[(size_t)j * 512];             // reused x4 across b
        acc.x += xv.x * fv.x; acc.y += xv.y * fv.y;
        acc.z += xv.z * fv.z; acc.w += xv.w * fv.w;
    }
    float s1 = acc.x + acc.y + acc.z + acc.w;
    float s2 = acc.x * acc.x + acc.y * acc.y + acc.z * acc.z + acc.w * acc.w;
    for (int off = 8; off; off >>= 1) {
        s1 += __shfl_xor(s1, off);
        s2 += __shfl_xor(s2, off);
    }
    float m = s1 * (1.f / 64.f);
    float var = s2 * (1.f / 64.f) - m * m;
    float rs = rsqrtf(var + EPSF);
    float4 gv = ((const float4*)g)[t4 & 15];
    float4 bv = ((const float4*)bia)[t4 & 15];
    float4 yv;
    yv.x = (acc.x - m) * rs * gv.x + bv.x;
    yv.y = (acc.y - m) * rs * gv.y + bv.y;
    yv.z = (acc.z - m) * rs * gv.z + bv.z;
    yv.w = (acc.w - m) * rs * gv.w + bv.w;
    size_t oidx = (size_t)b * 32768 + (size_t)i * 512 + t4;
    ((float4*)h)[oidx] = acc;
    ((float4*)y)[oidx] = yv;
    __shared__ float ysL[64];
    if (threadIdx.x < 64) ysL[threadIdx.x] = 0.f;
    __syncthreads();
    int c0 = (t4 & 15) * 4;
    atomicAdd(&ysL[c0 + 0], yv.x);
    atomicAdd(&ysL[c0 + 1], yv.y);
    atomicAdd(&ysL[c0 + 2], yv.z);
    atomicAdd(&ysL[c0 + 3], yv.w);
    __syncthreads();
    if (threadIdx.x < 64)
        part[(panel * 4 + b) * 64 + threadIdx.x] = ysL[threadIdx.x];
}

// ------ K2: inline ck from part; e = exp((y@Wq)*ck - OFFS); esum partials ---
__global__ void K2(const float* __restrict__ y, const float* __restrict__ wq,
                   const float* __restrict__ wk, const float* __restrict__ part,
                   float* __restrict__ e, float* __restrict__ esum) {
    __shared__ float yT[64][20];
    __shared__ float wqL[64][64];
    __shared__ float psum[4][64];
    __shared__ float psA[4][64];
    __shared__ float ysL[64];
    int b = blockIdx.x, tile = blockIdx.y, t0 = tile * 16;
    int tid = threadIdx.x;
    int c = tid & 63, grp = tid >> 6;
    // reduce part -> ysum (this block's b), distributed (32 loads/thread)
    float sA = 0.f;
    for (int pp = 0; pp < 32; ++pp)
        sA += part[((grp * 32 + pp) * 4 + b) * 64 + c];
    psA[grp][c] = sA;
    for (int k = 0; k < 4; ++k) {
        int idx = k * 256 + tid;
        int r = idx >> 6, s = idx & 63;
        yT[s][r] = y[(size_t)b * 131072 + (size_t)(t0 + r) * 64 + s];
    }
    for (int k = 0; k < 16; ++k) {
        int idx = k * 256 + tid;
        int r = idx >> 6, cc = idx & 63;
        wqL[r][cc] = wq[(cc >> 3) * 512 + r * 8 + (cc & 7)];
    }
    __syncthreads();
    if (tid < 64)
        ysL[tid] = psA[0][tid] + psA[1][tid] + psA[2][tid] + psA[3][tid];
    __syncthreads();
    // ck for column c (4x redundant across grp, cheap)
    float ckc = 0.f;
    for (int s = 0; s < 64; ++s)
        ckc += ysL[s] * wk[(c >> 3) * 512 + s * 8 + (c & 7)];
    float acc[4] = {0.f, 0.f, 0.f, 0.f};
    for (int s = 0; s < 64; ++s) {
        float w = wqL[s][c];
        float4 a0 = *(const float4*)&yT[s][grp * 4];
        acc[0] += a0.x * w; acc[1] += a0.y * w;
        acc[2] += a0.z * w; acc[3] += a0.w * w;
    }
    float ls = 0.f;
    #pragma unroll
    for (int k = 0; k < 4; ++k) {
        float v = __expf(acc[k] * ckc - OFFS);
        e[(size_t)b * 131072 + (size_t)(t0 + grp * 4 + k) * 64 + c] = v;
        ls += v;
    }
    psum[grp][c] = ls;
    __syncthreads();
    if (tid < 64)
        esum[(b * 128 + tile) * 64 + tid] =
            psum[0][tid] + psum[1][tid] + psum[2][tid] + psum[3][tid];
}

// ------ K3m: inline cv/scl; proj+LN2+FFN (LDS weights) -> hf ----------------
// Block (b, chunk of 16 rows): 4 waves x 4 rows. ~46KB LDS -> 3 blocks/CU.
__global__ void __launch_bounds__(256, 3)
K3m(const float* __restrict__ h, const float* __restrict__ e,
    const float* __restrict__ part, const float* __restrict__ esum,
    const float* __restrict__ wv, const float* __restrict__ projw,
    const float* __restrict__ projb, const float* __restrict__ g2,
    const float* __restrict__ b2l, const float* __restrict__ w1,
    const float* __restrict__ b1, const float* __restrict__ w2,
    const float* __restrict__ fb2, float* __restrict__ hf) {
    __shared__ float bufA[4096];      // projw, then w1 chunk [s][j]
    __shared__ float bufB[4096];      // w2 chunk [j][l]
    __shared__ float4 pT[4][64];
    __shared__ float4 y2T[4][64];
    __shared__ float4 hidT[4][64];
    __shared__ float psA[4][64], psE[4][64];
    __shared__ float ysL[64], denL[64];
    int b = blockIdx.x, chunk = blockIdx.y;
    int tid = threadIdx.x, l = tid & 63, w = tid >> 6;

    // stage projw
    float4* bufA4 = (float4*)bufA;
    const float4* pw4 = (const float4*)projw;
    #pragma unroll
    for (int k = 0; k < 4; ++k) bufA4[k * 256 + tid] = pw4[k * 256 + tid];
    // partial reduces for ysum (->cv) and den, distributed
    float sA = 0.f, sE = 0.f;
    for (int pp = 0; pp < 32; ++pp) {
        sA += part[((w * 32 + pp) * 4 + b) * 64 + l];
        sE += esum[(b * 128 + w * 32 + pp) * 64 + l];
    }
    psA[w][l] = sA;
    psE[w][l] = sE;
    __syncthreads();
    if (tid < 64) {
        ysL[tid] = psA[0][tid] + psA[1][tid] + psA[2][tid] + psA[3][tid];
        denL[tid] = psE[0][tid] + psE[1][tid] + psE[2][tid] + psE[3][tid];
    }
    __syncthreads();
    float cvv = 0.f;
    for (int s = 0; s < 64; ++s)
        cvv += ysL[s] * wv[(l >> 3) * 512 + s * 8 + (l & 7)];
    float sc = cvv / denL[l];

    size_t base = (size_t)b * 131072 + (size_t)(chunk * 16 + w * 4) * 64 + l;
    float4 p;
    p.x = e[base] * sc;
    p.y = e[base + 64] * sc;
    p.z = e[base + 128] * sc;
    p.w = e[base + 192] * sc;
    pT[w][l] = p;
    float h0 = h[base], h1r = h[base + 64], h2r = h[base + 128], h3r = h[base + 192];
    __syncthreads();

    // proj from LDS
    float a[4] = {0.f, 0.f, 0.f, 0.f};
    for (int c = 0; c < 64; ++c) {
        float4 pv = pT[w][c];
        float pw = bufA[c * 64 + l];
        a[0] += pv.x * pw; a[1] += pv.y * pw;
        a[2] += pv.z * pw; a[3] += pv.w * pw;
    }
    float pb = projb[l], g2v = g2[l], b2v = b2l[l];
    float hmid[4] = {h0 + a[0] + pb, h1r + a[1] + pb, h2r + a[2] + pb, h3r + a[3] + pb};
    float y2[4];
    #pragma unroll
    for (int rr = 0; rr < 4; ++rr) {
        float v = hmid[rr];
        float s1 = v, s2 = v * v;
        for (int off = 32; off; off >>= 1) {
            s1 += __shfl_xor(s1, off);
            s2 += __shfl_xor(s2, off);
        }
        float mm = s1 * (1.f / 64.f);
        float var = s2 * (1.f / 64.f) - mm * mm;
        float rs = rsqrtf(var + EPSF);
        y2[rr] = (v - mm) * rs * g2v + b2v;
    }
    y2T[w][l] = make_float4(y2[0], y2[1], y2[2], y2[3]);
    __syncthreads();   // proj done with bufA; y2T visible

    // FFN in 4 chunks of 64 hidden units
    float4* bufB4 = (float4*)bufB;
    const float4* w14 = (const float4*)w1;
    const float4* w24 = (const float4*)w2;
    float a2[4] = {0.f, 0.f, 0.f, 0.f};
    for (int c4 = 0; c4 < 4; ++c4) {
        #pragma unroll
        for (int k = 0; k < 4; ++k) {
            int f = k * 256 + tid;
            int r = f >> 4, q = f & 15;
            bufA4[r * 16 + q] = w14[r * 64 + c4 * 16 + q];           // w1c[s][j]
            bufB4[r * 16 + q] = w24[(size_t)(c4 * 64 + r) * 16 + q]; // w2c[j][l]
        }
        __syncthreads();
        float bb = b1[c4 * 64 + l];
        float hc[4] = {bb, bb, bb, bb};
        for (int s = 0; s < 64; ++s) {
            float4 yv = y2T[w][s];
            float w1v = bufA[s * 64 + l];
            hc[0] += yv.x * w1v; hc[1] += yv.y * w1v;
            hc[2] += yv.z * w1v; hc[3] += yv.w * w1v;
        }
        hidT[w][l] = make_float4(fmaxf(hc[0], 0.f), fmaxf(hc[1], 0.f),
                                 fmaxf(hc[2], 0.f), fmaxf(hc[3], 0.f));
        for (int j = 0; j < 64; ++j) {          // same-wave LDS, no barrier
            float4 hv = hidT[w][j];
            float w2v = bufB[j * 64 + l];
            a2[0] += hv.x * w2v; a2[1] += hv.y * w2v;
            a2[2] += hv.z * w2v; a2[3] += hv.w * w2v;
        }
        __syncthreads();   // protect bufA/bufB for next chunk
    }
    float fb = fb2[l];
    hf[base]       = hmid[0] + a2[0] + fb;
    hf[base + 64]  = hmid[1] + a2[1] + fb;
    hf[base + 128] = hmid[2] + a2[2] + fb;
    hf[base + 192] = hmid[3] + a2[3] + fb;
}

// ------ K5: Booster. out[b,i,j,t'] = bw[i,j,t'] * hf[b, j*2048+t'] ----------
// Each bw float4 read by exactly one thread (nontemporal); hf stays L2-hot
// (64x reuse across i); out stores nontemporal (never re-read).
__global__ void K5(const float* __restrict__ hf, const float* __restrict__ bw,
                   float* __restrict__ out) {
    int wi = blockIdx.x * 256 + threadIdx.x;    // float4 index into bw
    int i = wi >> 15;
    int jt = wi & 32767;                        // j*512 + t4
    const float4* bw4 = (const float4*)bw;
    const float4* hf4 = (const float4*)hf;
    float4* o4 = (float4*)out;
    float4 wv = ntload4(&bw4[wi]);
    size_t obase = (size_t)i * 32768 + jt;
    #pragma unroll
    for (int b = 0; b < 4; ++b) {
        float4 hv = hf4[b * 32768 + jt];
        float4 ov;
        ov.x = wv.x * hv.x; ov.y = wv.y * hv.y;
        ov.z = wv.z * hv.z; ov.w = wv.w * hv.w;
        ntstore4(&o4[(size_t)b * 2097152 + obase], ov);
    }
}

extern "C" void kernel_launch(void* const* d_in, const int* in_sizes, int n_in,
                              void* d_out, int out_size, void* d_ws, size_t ws_size,
                              hipStream_t stream) {
    const float* x     = (const float*)d_in[0];
    const float* fw    = (const float*)d_in[1];
    const float* bw    = (const float*)d_in[2];
    const float* wq    = (const float*)d_in[3];
    const float* wk    = (const float*)d_in[4];
    const float* wv    = (const float*)d_in[5];
    const float* projw = (const float*)d_in[6];
    const float* projb = (const float*)d_in[7];
    const float* g1    = (const float*)d_in[8];
    const float* b1l   = (const float*)d_in[9];
    const float* g2    = (const float*)d_in[10];
    const float* b2l   = (const float*)d_in[11];
    const float* w1    = (const float*)d_in[12];
    const float* b1    = (const float*)d_in[13];
    const float* w2    = (const float*)d_in[14];
    const float* b2    = (const float*)d_in[15];
    float* out = (float*)d_out;

    float* wsf = (float*)d_ws;
    float* h    = wsf;                 // 524288
    float* y    = wsf + 524288;        // 524288 (reused as hf after K2)
    float* hf   = wsf + 524288;        //   - y dead after K2; hf live K3m->K5
    float* e    = wsf + 1048576;       // 524288
    float* part = wsf + 1572864;       // 32768
    float* esum = wsf + 1605632;       // 32768

    K1 <<<512, 256, 0, stream>>>(x, fw, g1, b1l, h, y, part);
    K2 <<<dim3(4, 128), 256, 0, stream>>>(y, wq, wk, part, e, esum);
    K3m<<<dim3(4, 128), 256, 0, stream>>>(h, e, part, esum, wv, projw, projb,
                                          g2, b2l, w1, b1, w2, b2, hf);
    K5 <<<8192, 256, 0, stream>>>(hf, bw, out);
}

// Round 14
// 114.190 us; speedup vs baseline: 3.4737x; 1.0641x over previous
//
#include <hip/hip_runtime.h>
#include <hip/hip_bf16.h>

// B=4, T=2048, SD=64, NE=4096, H=8, HS=8, FH=256. All reference reshapes are
// flat reinterpretations -> one flat buffer serves every "view".
// h/y/e/hf flat element (t,l): b*131072 + t*64 + l.
// x viewed (B,SD,SD,T): b*4194304 + i*131072 + j*2048 + t.
// out viewed (B,SD,SD,T): b*8388608 + i*131072 + j*2048 + t.
// Softmax: shift-invariant; fixed offset exp(qc-40) -> no global-max pass.
// R13 baseline (121.5us) + K1 split-j 512-thread variant (16 waves/CU).

#define EPSF 1e-5f
#define OFFS 40.0f

typedef float vfloat4 __attribute__((ext_vector_type(4)));

__device__ __forceinline__ float4 ntload4(const float4* p) {
    vfloat4 v = __builtin_nontemporal_load((const vfloat4*)p);
    return make_float4(v.x, v.y, v.z, v.w);
}
__device__ __forceinline__ void ntstore4(float4* p, float4 v) {
    vfloat4 t = {v.x, v.y, v.z, v.w};
    __builtin_nontemporal_store(t, (vfloat4*)p);
}

// ------ K1: Feebler + LayerNorm1 + per-block column partial sums ------------
// 512 blocks x 512 threads, XCD-swizzled (4 b-blocks of one fw panel -> one
// XCD under round-robin). Two thread-halves split the j-reduction (32 terms
// each -> half the load chain, 16 waves/CU), combined via LDS; LN + column
// partials on the lower half (wave-uniform branch).
__global__ void K1(const float* __restrict__ x, const float* __restrict__ fw,
                   const float* __restrict__ g, const float* __restrict__ bia,
                   float* __restrict__ h, float* __restrict__ y,
                   float* __restrict__ part) {
    int bid = blockIdx.x;
    int xcd = bid & 7, slot = bid >> 3;
    int b = slot & 3;
    int panel = (slot >> 2) * 8 + xcd;          // 0..127 = chunk*64 + i
    int i = panel & 63, chunk = panel >> 6;
    int tid = threadIdx.x;
    int half = tid >> 8;                        // 0 | 1 (wave-uniform)
    int t4 = chunk * 256 + (tid & 255);         // float4 idx 0..511 in (b,i)
    const float4* x4 = (const float4*)x + (size_t)b * 2097152 + (size_t)i * 32768 + t4;
    const float4* f4 = (const float4*)fw + (size_t)i * 32768 + t4;
    float4 acc = make_float4(0.f, 0.f, 0.f, 0.f);
    int j0 = half * 32;
    #pragma unroll 8
    for (int jj = 0; jj < 32; ++jj) {
        int j = j0 + jj;
        float4 xv = ntload4(&x4[(size_t)j * 512]);   // read-once stream
        float4 fv = f4[(size_t)j * 512];             // reused across b (L2)
        acc.x += xv.x * fv.x; acc.y += xv.y * fv.y;
        acc.z += xv.z * fv.z; acc.w += xv.w * fv.w;
    }
    __shared__ float4 accbuf[256];
    __shared__ float ysL[64];
    if (half) accbuf[tid & 255] = acc;
    __syncthreads();
    if (tid < 64) ysL[tid] = 0.f;
    float4 yv = make_float4(0.f, 0.f, 0.f, 0.f);
    if (!half) {
        float4 o = accbuf[tid];
        acc.x += o.x; acc.y += o.y; acc.z += o.z; acc.w += o.w;
        // LN over the 64-col row: 16 consecutive lanes per row (same wave).
        float s1 = acc.x + acc.y + acc.z + acc.w;
        float s2 = acc.x * acc.x + acc.y * acc.y + acc.z * acc.z + acc.w * acc.w;
        for (int off = 8; off; off >>= 1) {
            s1 += __shfl_xor(s1, off);
            s2 += __shfl_xor(s2, off);
        }
        float m = s1 * (1.f / 64.f);
        float var = s2 * (1.f / 64.f) - m * m;
        float rs = rsqrtf(var + EPSF);
        float4 gv = ((const float4*)g)[t4 & 15];
        float4 bv = ((const float4*)bia)[t4 & 15];
        yv.x = (acc.x - m) * rs * gv.x + bv.x;
        yv.y = (acc.y - m) * rs * gv.y + bv.y;
        yv.z = (acc.z - m) * rs * gv.z + bv.z;
        yv.w = (acc.w - m) * rs * gv.w + bv.w;
        size_t oidx = (size_t)b * 32768 + (size_t)i * 512 + t4;
        ((float4*)h)[oidx] = acc;
        ((float4*)y)[oidx] = yv;
    }
    __syncthreads();        // ysL zeroed AND yv ready
    if (!half) {
        int c0 = (t4 & 15) * 4;
        atomicAdd(&ysL[c0 + 0], yv.x);
        atomicAdd(&ysL[c0 + 1], yv.y);
        atomicAdd(&ysL[c0 + 2], yv.z);
        atomicAdd(&ysL[c0 + 3], yv.w);
    }
    __syncthreads();
    if (tid < 64)
        part[(panel * 4 + b) * 64 + tid] = ysL[tid];
}

// ------ K2: inline ck from part; e = exp((y@Wq)*ck - OFFS); esum partials ---
__global__ void K2(const float* __restrict__ y, const float* __restrict__ wq,
                   const float* __restrict__ wk, const float* __restrict__ part,
                   float* __restrict__ e, float* __restrict__ esum) {
    __shared__ float yT[64][20];
    __shared__ float wqL[64][64];
    __shared__ float psum[4][64];
    __shared__ float psA[4][64];
    __shared__ float ysL[64];
    int b = blockIdx.x, tile = blockIdx.y, t0 = tile * 16;
    int tid = threadIdx.x;
    int c = tid & 63, grp = tid >> 6;
    // reduce part -> ysum (this block's b), distributed (32 loads/thread)
    float sA = 0.f;
    for (int pp = 0; pp < 32; ++pp)
        sA += part[((grp * 32 + pp) * 4 + b) * 64 + c];
    psA[grp][c] = sA;
    for (int k = 0; k < 4; ++k) {
        int idx = k * 256 + tid;
        int r = idx >> 6, s = idx & 63;
        yT[s][r] = y[(size_t)b * 131072 + (size_t)(t0 + r) * 64 + s];
    }
    for (int k = 0; k < 16; ++k) {
        int idx = k * 256 + tid;
        int r = idx >> 6, cc = idx & 63;
        wqL[r][cc] = wq[(cc >> 3) * 512 + r * 8 + (cc & 7)];
    }
    __syncthreads();
    if (tid < 64)
        ysL[tid] = psA[0][tid] + psA[1][tid] + psA[2][tid] + psA[3][tid];
    __syncthreads();
    // ck for column c (4x redundant across grp, cheap)
    float ckc = 0.f;
    for (int s = 0; s < 64; ++s)
        ckc += ysL[s] * wk[(c >> 3) * 512 + s * 8 + (c & 7)];
    float acc[4] = {0.f, 0.f, 0.f, 0.f};
    for (int s = 0; s < 64; ++s) {
        float w = wqL[s][c];
        float4 a0 = *(const float4*)&yT[s][grp * 4];
        acc[0] += a0.x * w; acc[1] += a0.y * w;
        acc[2] += a0.z * w; acc[3] += a0.w * w;
    }
    float ls = 0.f;
    #pragma unroll
    for (int k = 0; k < 4; ++k) {
        float v = __expf(acc[k] * ckc - OFFS);
        e[(size_t)b * 131072 + (size_t)(t0 + grp * 4 + k) * 64 + c] = v;
        ls += v;
    }
    psum[grp][c] = ls;
    __syncthreads();
    if (tid < 64)
        esum[(b * 128 + tile) * 64 + tid] =
            psum[0][tid] + psum[1][tid] + psum[2][tid] + psum[3][tid];
}

// ------ K3m: inline cv/scl; proj+LN2+FFN (LDS weights) -> hf ----------------
// Block (b, chunk of 16 rows): 4 waves x 4 rows. ~46KB LDS -> 3 blocks/CU.
__global__ void __launch_bounds__(256, 3)
K3m(const float* __restrict__ h, const float* __restrict__ e,
    const float* __restrict__ part, const float* __restrict__ esum,
    const float* __restrict__ wv, const float* __restrict__ projw,
    const float* __restrict__ projb, const float* __restrict__ g2,
    const float* __restrict__ b2l, const float* __restrict__ w1,
    const float* __restrict__ b1, const float* __restrict__ w2,
    const float* __restrict__ fb2, float* __restrict__ hf) {
    __shared__ float bufA[4096];      // projw, then w1 chunk [s][j]
    __shared__ float bufB[4096];      // w2 chunk [j][l]
    __shared__ float4 pT[4][64];
    __shared__ float4 y2T[4][64];
    __shared__ float4 hidT[4][64];
    __shared__ float psA[4][64], psE[4][64];
    __shared__ float ysL[64], denL[64];
    int b = blockIdx.x, chunk = blockIdx.y;
    int tid = threadIdx.x, l = tid & 63, w = tid >> 6;

    // stage projw
    float4* bufA4 = (float4*)bufA;
    const float4* pw4 = (const float4*)projw;
    #pragma unroll
    for (int k = 0; k < 4; ++k) bufA4[k * 256 + tid] = pw4[k * 256 + tid];
    // partial reduces for ysum (->cv) and den, distributed
    float sA = 0.f, sE = 0.f;
    for (int pp = 0; pp < 32; ++pp) {
        sA += part[((w * 32 + pp) * 4 + b) * 64 + l];
        sE += esum[(b * 128 + w * 32 + pp) * 64 + l];
    }
    psA[w][l] = sA;
    psE[w][l] = sE;
    __syncthreads();
    if (tid < 64) {
        ysL[tid] = psA[0][tid] + psA[1][tid] + psA[2][tid] + psA[3][tid];
        denL[tid] = psE[0][tid] + psE[1][tid] + psE[2][tid] + psE[3][tid];
    }
    __syncthreads();
    float cvv = 0.f;
    for (int s = 0; s < 64; ++s)
        cvv += ysL[s] * wv[(l >> 3) * 512 + s * 8 + (l & 7)];
    float sc = cvv / denL[l];

    size_t base = (size_t)b * 131072 + (size_t)(chunk * 16 + w * 4) * 64 + l;
    float4 p;
    p.x = e[base] * sc;
    p.y = e[base + 64] * sc;
    p.z = e[base + 128] * sc;
    p.w = e[base + 192] * sc;
    pT[w][l] = p;
    float h0 = h[base], h1r = h[base + 64], h2r = h[base + 128], h3r = h[base + 192];
    __syncthreads();

    // proj from LDS
    float a[4] = {0.f, 0.f, 0.f, 0.f};
    for (int c = 0; c < 64; ++c) {
        float4 pv = pT[w][c];
        float pw = bufA[c * 64 + l];
        a[0] += pv.x * pw; a[1] += pv.y * pw;
        a[2] += pv.z * pw; a[3] += pv.w * pw;
    }
    float pb = projb[l], g2v = g2[l], b2v = b2l[l];
    float hmid[4] = {h0 + a[0] + pb, h1r + a[1] + pb, h2r + a[2] + pb, h3r + a[3] + pb};
    float y2[4];
    #pragma unroll
    for (int rr = 0; rr < 4; ++rr) {
        float v = hmid[rr];
        float s1 = v, s2 = v * v;
        for (int off = 32; off; off >>= 1) {
            s1 += __shfl_xor(s1, off);
            s2 += __shfl_xor(s2, off);
        }
        float mm = s1 * (1.f / 64.f);
        float var = s2 * (1.f / 64.f) - mm * mm;
        float rs = rsqrtf(var + EPSF);
        y2[rr] = (v - mm) * rs * g2v + b2v;
    }
    y2T[w][l] = make_float4(y2[0], y2[1], y2[2], y2[3]);
    __syncthreads();   // proj done with bufA; y2T visible

    // FFN in 4 chunks of 64 hidden units
    float4* bufB4 = (float4*)bufB;
    const float4* w14 = (const float4*)w1;
    const float4* w24 = (const float4*)w2;
    float a2[4] = {0.f, 0.f, 0.f, 0.f};
    for (int c4 = 0; c4 < 4; ++c4) {
        #pragma unroll
        for (int k = 0; k < 4; ++k) {
            int f = k * 256 + tid;
            int r = f >> 4, q = f & 15;
            bufA4[r * 16 + q] = w14[r * 64 + c4 * 16 + q];           // w1c[s][j]
            bufB4[r * 16 + q] = w24[(size_t)(c4 * 64 + r) * 16 + q]; // w2c[j][l]
        }
        __syncthreads();
        float bb = b1[c4 * 64 + l];
        float hc[4] = {bb, bb, bb, bb};
        for (int s = 0; s < 64; ++s) {
            float4 yv = y2T[w][s];
            float w1v = bufA[s * 64 + l];
            hc[0] += yv.x * w1v; hc[1] += yv.y * w1v;
            hc[2] += yv.z * w1v; hc[3] += yv.w * w1v;
        }
        hidT[w][l] = make_float4(fmaxf(hc[0], 0.f), fmaxf(hc[1], 0.f),
                                 fmaxf(hc[2], 0.f), fmaxf(hc[3], 0.f));
        for (int j = 0; j < 64; ++j) {          // same-wave LDS, no barrier
            float4 hv = hidT[w][j];
            float w2v = bufB[j * 64 + l];
            a2[0] += hv.x * w2v; a2[1] += hv.y * w2v;
            a2[2] += hv.z * w2v; a2[3] += hv.w * w2v;
        }
        __syncthreads();   // protect bufA/bufB for next chunk
    }
    float fb = fb2[l];
    hf[base]       = hmid[0] + a2[0] + fb;
    hf[base + 64]  = hmid[1] + a2[1] + fb;
    hf[base + 128] = hmid[2] + a2[2] + fb;
    hf[base + 192] = hmid[3] + a2[3] + fb;
}

// ------ K5: Booster. out[b,i,j,t'] = bw[i,j,t'] * hf[b, j*2048+t'] ----------
// Each bw float4 read by exactly one thread (nontemporal); hf stays L2-hot
// (64x reuse across i); out stores nontemporal (never re-read).
__global__ void K5(const float* __restrict__ hf, const float* __restrict__ bw,
                   float* __restrict__ out) {
    int wi = blockIdx.x * 256 + threadIdx.x;    // float4 index into bw
    int i = wi >> 15;
    int jt = wi & 32767;                        // j*512 + t4
    const float4* bw4 = (const float4*)bw;
    const float4* hf4 = (const float4*)hf;
    float4* o4 = (float4*)out;
    float4 wv = ntload4(&bw4[wi]);
    size_t obase = (size_t)i * 32768 + jt;
    #pragma unroll
    for (int b = 0; b < 4; ++b) {
        float4 hv = hf4[b * 32768 + jt];
        float4 ov;
        ov.x = wv.x * hv.x; ov.y = wv.y * hv.y;
        ov.z = wv.z * hv.z; ov.w = wv.w * hv.w;
        ntstore4(&o4[(size_t)b * 2097152 + obase], ov);
    }
}

extern "C" void kernel_launch(void* const* d_in, const int* in_sizes, int n_in,
                              void* d_out, int out_size, void* d_ws, size_t ws_size,
                              hipStream_t stream) {
    const float* x     = (const float*)d_in[0];
    const float* fw    = (const float*)d_in[1];
    const float* bw    = (const float*)d_in[2];
    const float* wq    = (const float*)d_in[3];
    const float* wk    = (const float*)d_in[4];
    const float* wv    = (const float*)d_in[5];
    const float* projw = (const float*)d_in[6];
    const float* projb = (const float*)d_in[7];
    const float* g1    = (const float*)d_in[8];
    const float* b1l   = (const float*)d_in[9];
    const float* g2    = (const float*)d_in[10];
    const float* b2l   = (const float*)d_in[11];
    const float* w1    = (const float*)d_in[12];
    const float* b1    = (const float*)d_in[13];
    const float* w2    = (const float*)d_in[14];
    const float* b2    = (const float*)d_in[15];
    float* out = (float*)d_out;

    float* wsf = (float*)d_ws;
    float* h    = wsf;                 // 524288
    float* y    = wsf + 524288;        // 524288 (reused as hf after K2)
    float* hf   = wsf + 524288;        //   - y dead after K2; hf live K3m->K5
    float* e    = wsf + 1048576;       // 524288
    float* part = wsf + 1572864;       // 32768
    float* esum = wsf + 1605632;       // 32768

    K1 <<<512, 512, 0, stream>>>(x, fw, g1, b1l, h, y, part);
    K2 <<<dim3(4, 128), 256, 0, stream>>>(y, wq, wk, part, e, esum);
    K3m<<<dim3(4, 128), 256, 0, stream>>>(h, e, part, esum, wv, projw, projb,
                                          g2, b2l, w1, b1, w2, b2, hf);
    K5 <<<8192, 256, 0, stream>>>(hf, bw, out);
}